// Round 17
// baseline (104.857 us; speedup 1.0000x reference)
//
#include <hip/hip_runtime.h>
#include <hip/hip_bf16.h>

#define NV   200000
#define KN   32
#define TPB  256
#define NSLICE 4
#define SLICEW 50000   // NV / NSLICE; 50000*32B = 1.6 MB slice, L2-resident per XCD

// native clang vector types (valid for __builtin_nontemporal_*; same layout
// as HIP float4/int4)
typedef int   intx4   __attribute__((ext_vector_type(4)));
typedef float floatx4 __attribute__((ext_vector_type(4)));

// ===== LAPACK float32 machine constants =====
#define F_EPS  5.9604645e-8f    /* slamch('E') = 2^-24 */
#define F_UNFL 1.1754944e-38f   /* slamch('S') */
#define F_TOL  (10.0f * F_EPS)  /* tolmul = 10 */

// ===== fast math: conventions (signs/branches) follow LAPACK; 1-2 ulp
// rounding differences only flip decisions on measure-zero boundary sets.
__device__ __forceinline__ float fdiv_(float a, float b) { return __fdividef(a, b); }
__device__ __forceinline__ float fsqrt_(float x) { return __builtin_amdgcn_sqrtf(x); }

// ---- pack V / V_def into interleaved 32B records in workspace ---------------
// P[n] = { vx, vy, vz, dx, dy, dz, 0, 0 }
__global__ __launch_bounds__(256) void pack_kernel(const float* __restrict__ V,
                                                   const float* __restrict__ Vd,
                                                   float* __restrict__ wsf) {
    int i = blockIdx.x * 256 + threadIdx.x;
    if (i < NV * 3) {
        int n = i / 3;
        int c = i - n * 3;
        wsf[(size_t)n * 8 + c]     = V[i];
        wsf[(size_t)n * 8 + 3 + c] = Vd[i];
    }
}

// ===== LAPACK >=3.10 slartg (f32) ===========================================
__device__ __forceinline__ void slartg_(float f, float g, float& c, float& s, float& r) {
    if (g == 0.0f)      { c = 1.0f; s = 0.0f; r = f; }
    else if (f == 0.0f) { c = 0.0f; s = copysignf(1.0f, g); r = fabsf(g); }
    else {
        float d = fsqrt_(f * f + g * g);
        c = fdiv_(fabsf(f), d);
        r = copysignf(d, f);
        s = fdiv_(g, r);
    }
}

// ===== LAPACK slas2 (exactly symmetric under f<->h) =========================
__device__ __forceinline__ void slas2_(float f, float g, float h, float& ssmin, float& ssmax) {
    float fa = fabsf(f), ga = fabsf(g), ha = fabsf(h);
    float fhmn = fminf(fa, ha), fhmx = fmaxf(fa, ha);
    if (fhmn == 0.0f) {
        ssmin = 0.0f;
        if (fhmx == 0.0f) ssmax = ga;
        else {
            float mx = fmaxf(fhmx, ga), mn = fminf(fhmx, ga);
            float q = fdiv_(mn, mx);
            ssmax = mx * fsqrt_(1.0f + q * q);
        }
    } else {
        if (ga < fhmx) {
            float as_ = 1.0f + fdiv_(fhmn, fhmx);
            float at  = fdiv_(fhmx - fhmn, fhmx);
            float au  = fdiv_(ga, fhmx); au = au * au;
            float c   = fdiv_(2.0f, fsqrt_(as_ * as_ + au) + fsqrt_(at * at + au));
            ssmin = fhmn * c;
            ssmax = fdiv_(fhmx, c);
        } else {
            float au = fdiv_(fhmx, ga);
            if (au == 0.0f) { ssmin = fdiv_(fhmn * fhmx, ga); ssmax = ga; }
            else {
                float as_ = 1.0f + fdiv_(fhmn, fhmx);
                float at  = fdiv_(fhmx - fhmn, fhmx);
                float t1 = as_ * au, t2 = at * au;
                float c = fdiv_(1.0f, fsqrt_(1.0f + t1 * t1) + fsqrt_(1.0f + t2 * t2));
                ssmin = (fhmn * c) * au;
                ssmin = ssmin + ssmin;
                ssmax = fdiv_(ga, c + c);
            }
        }
    }
}

// ===== LAPACK slasv2 ========================================================
__device__ void slasv2_(float f, float g, float h,
                        float& ssmin, float& ssmax,
                        float& snr, float& csr, float& snl, float& csl) {
    float ft = f, fa = fabsf(f), ht = h, ha = fabsf(h);
    int pmax = 1;
    bool swp = (ha > fa);
    if (swp) {
        pmax = 3;
        float t = ft; ft = ht; ht = t;
        t = fa; fa = ha; ha = t;
    }
    float gt = g, ga = fabsf(g);
    float clt = 0.f, crt = 0.f, slt = 0.f, srt = 0.f;
    if (ga == 0.0f) {
        ssmin = ha; ssmax = fa;
        clt = 1.0f; crt = 1.0f; slt = 0.0f; srt = 0.0f;
    } else {
        bool gasmal = true;
        if (ga > fa) {
            pmax = 2;
            if (fdiv_(fa, ga) < F_EPS) {
                gasmal = false;
                ssmax = ga;
                ssmin = (ha > 1.0f) ? fdiv_(fa, fdiv_(ga, ha)) : (fdiv_(fa, ga) * ha);
                clt = 1.0f; slt = fdiv_(ht, gt); srt = 1.0f; crt = fdiv_(ft, gt);
            }
        }
        if (gasmal) {
            float dd = fa - ha;
            float l_ = (dd == fa) ? 1.0f : fdiv_(dd, fa);
            float m_ = fdiv_(gt, ft);
            float t_ = 2.0f - l_;
            float mm = m_ * m_, tt = t_ * t_;
            float s_ = fsqrt_(tt + mm);
            float r_ = (l_ == 0.0f) ? fabsf(m_) : fsqrt_(l_ * l_ + mm);
            float a_ = 0.5f * (s_ + r_);
            ssmin = fdiv_(ha, a_);
            ssmax = fa * a_;
            float tv;
            if (mm == 0.0f) {
                if (l_ == 0.0f) tv = copysignf(2.0f, ft) * copysignf(1.0f, gt);
                else            tv = fdiv_(gt, copysignf(dd, ft)) + fdiv_(m_, t_);
            } else {
                tv = (fdiv_(m_, s_ + t_) + fdiv_(m_, r_ + l_)) * (1.0f + a_);
            }
            float l2 = fsqrt_(tv * tv + 4.0f);
            crt = fdiv_(2.0f, l2);
            srt = fdiv_(tv, l2);
            clt = fdiv_(crt + srt * m_, a_);
            slt = fdiv_(ht, ft) * fdiv_(srt, a_);
        }
    }
    if (swp) { csl = srt; snl = crt; csr = slt; snr = clt; }
    else     { csl = clt; snl = slt; csr = crt; snr = srt; }
    float tsign = 1.0f;
    if (pmax == 1) tsign = copysignf(1.0f, csr) * copysignf(1.0f, csl) * copysignf(1.0f, f);
    if (pmax == 2) tsign = copysignf(1.0f, snr) * copysignf(1.0f, csl) * copysignf(1.0f, g);
    if (pmax == 3) tsign = copysignf(1.0f, snr) * copysignf(1.0f, snl) * copysignf(1.0f, h);
    ssmax = copysignf(ssmax, tsign);
    ssmin = copysignf(ssmin, tsign * copysignf(1.0f, f) * copysignf(1.0f, h));
}

// ===== static-index helpers =================================================
template<int RA, int RB>
__device__ __forceinline__ void rot_rows(float A[3][3], float c, float s) {
    #pragma unroll
    for (int j = 0; j < 3; ++j) {
        float x = A[RA][j], y = A[RB][j];
        A[RA][j] = c * x + s * y;
        A[RB][j] = c * y - s * x;
    }
}
template<int CA, int CB>
__device__ __forceinline__ void rot_cols(float A[3][3], float c, float s) {
    #pragma unroll
    for (int i = 0; i < 3; ++i) {
        float x = A[i][CA], y = A[i][CB];
        A[i][CA] = c * x + s * y;
        A[i][CB] = c * y - s * x;
    }
}
template<int RA, int RB>
__device__ __forceinline__ void swap_rows(float A[3][3]) {
    #pragma unroll
    for (int j = 0; j < 3; ++j) { float t = A[RA][j]; A[RA][j] = A[RB][j]; A[RB][j] = t; }
}
template<int CA, int CB>
__device__ __forceinline__ void swap_cols(float A[3][3]) {
    #pragma unroll
    for (int i = 0; i < 3; ++i) { float t = A[i][CA]; A[i][CA] = A[i][CB]; A[i][CB] = t; }
}

// ===== SBDSQR for n=3: single-direction via exact mirror ====================
// (idir==2 == J-conjugate of idir==1; mirror up front, run idir=1 loop only,
// un-mirror before the common epilogue. See round-13 derivation.)
__device__ void bdsqr3(float d[3], float e[2], float U[3][3], float VT[3][3]) {
    float thresh;
    {   // thresh on ORIGINAL orientation (LAPACK computes it before idir)
        float sminoa = fabsf(d[0]);
        if (sminoa != 0.0f) {
            float mu = sminoa;
            mu = fabsf(d[1]) * fdiv_(mu, mu + fabsf(e[0]));
            sminoa = fminf(sminoa, mu);
            if (sminoa != 0.0f) {
                mu = fabsf(d[2]) * fdiv_(mu, mu + fabsf(e[1]));
                sminoa = fminf(sminoa, mu);
            }
        }
        sminoa = sminoa * 0.57735026919f;   // /sqrt(3)
        thresh = fmaxf(F_TOL * sminoa, 54.0f * F_UNFL);
    }

    const bool mir = fabsf(d[0]) < fabsf(d[2]);
    if (mir) {
        float t = d[0]; d[0] = d[2]; d[2] = t;
        t = e[0]; e[0] = e[1]; e[1] = t;
        float Un[3][3], Vn[3][3];
        #pragma unroll
        for (int i = 0; i < 3; ++i)
            #pragma unroll
            for (int j = 0; j < 3; ++j) { Un[i][j] = VT[2 - j][i]; Vn[i][j] = U[j][2 - i]; }
        #pragma unroll
        for (int i = 0; i < 3; ++i)
            #pragma unroll
            for (int j = 0; j < 3; ++j) { U[i][j] = Un[i][j]; VT[i][j] = Vn[i][j]; }
    }

    int iter = 0;
    bool tail22 = false;   // deflated to leading 2x2 (rows 0..1)
    bool aborted = false;

    for (;;) {
        if (iter > 54) { aborted = true; break; }
        // ---- bottom-up negligibility scan (static) ----
        if (fabsf(e[1]) <= thresh) { e[1] = 0.0f; tail22 = true; break; }   // M: 3->2
        float smax = fmaxf(fabsf(d[2]), fmaxf(fabsf(e[1]), fabsf(d[1])));
        if (fabsf(e[0]) <= thresh) {
            // block = rows 1..2: 2x2 slasv2, then M=1 -> done
            e[0] = 0.0f;
            float sigmn, sigmx, sinr, cosr, sinl, cosl;
            slasv2_(d[1], e[1], d[2], sigmn, sigmx, sinr, cosr, sinl, cosl);
            d[1] = sigmx; d[2] = sigmn; e[1] = 0.0f;
            rot_rows<1, 2>(VT, cosr, sinr); rot_cols<1, 2>(U, cosl, sinl);
            break;
        }
        smax = fmaxf(smax, fmaxf(fabsf(e[0]), fabsf(d[0])));
        // ---- full 3x3 block, idir==1 semantics only (mirror guarantees) ----
        float sminl = 0.0f;
        bool conv = false;
        {
            if (fabsf(e[1]) <= F_TOL * fabsf(d[2])) { e[1] = 0.0f; continue; }
            float mu = fabsf(d[0]); sminl = mu;
            if (fabsf(e[0]) <= F_TOL * mu) { e[0] = 0.0f; conv = true; }
            else {
                mu = fabsf(d[1]) * fdiv_(mu, mu + fabsf(e[0]));
                sminl = fminf(sminl, mu);
                if (fabsf(e[1]) <= F_TOL * mu) { e[1] = 0.0f; conv = true; }
                else {
                    mu = fabsf(d[2]) * fdiv_(mu, mu + fabsf(e[1]));
                    sminl = fminf(sminl, mu);
                }
            }
        }
        if (conv) continue;
        // ---- shift ----
        float shift = 0.0f, rdum;
        if (3.0f * F_TOL * fdiv_(sminl, smax) <= fmaxf(F_EPS, 0.01f * F_TOL)) {
            shift = 0.0f;
        } else {
            float sll = fabsf(d[0]);
            slas2_(d[1], e[1], d[2], shift, rdum);
            if (sll > 0.0f) { float q = fdiv_(shift, sll); if (q * q < F_EPS) shift = 0.0f; }
        }
        iter += 2;
        // ---- one QR sweep, idir==1 bodies only ----
        if (shift == 0.0f) {
            float cs = 1.0f, oldcs = 1.0f, sn, oldsn, r;
            float c1, s1, oc1, os1, c2, s2, oc2, os2;
            slartg_(d[0] * cs, e[0], cs, sn, r);
            slartg_(oldcs * r, d[1] * sn, oldcs, oldsn, d[0]);
            c1 = cs; s1 = sn; oc1 = oldcs; os1 = oldsn;
            slartg_(d[1] * cs, e[1], cs, sn, r);
            e[0] = oldsn * r;
            slartg_(oldcs * r, d[2] * sn, oldcs, oldsn, d[1]);
            c2 = cs; s2 = sn; oc2 = oldcs; os2 = oldsn;
            float h = d[2] * cs; d[2] = h * oldcs; e[1] = h * oldsn;
            rot_rows<0, 1>(VT, c1, s1);  rot_rows<1, 2>(VT, c2, s2);
            rot_cols<0, 1>(U, oc1, os1); rot_cols<1, 2>(U, oc2, os2);
            if (fabsf(e[1]) <= thresh) e[1] = 0.0f;
        } else {
            float f = (fabsf(d[0]) - shift) * (copysignf(1.0f, d[0]) + fdiv_(shift, d[0]));
            float g = e[0], cosr, sinr, cosl, sinl, r;
            float cr1, sr1, cl1, sl1, cr2, sr2, cl2, sl2;
            slartg_(f, g, cosr, sinr, r);
            f = cosr * d[0] + sinr * e[0];
            e[0] = cosr * e[0] - sinr * d[0];
            g = sinr * d[1];
            d[1] = cosr * d[1];
            slartg_(f, g, cosl, sinl, r);
            d[0] = r;
            f = cosl * e[0] + sinl * d[1];
            d[1] = cosl * d[1] - sinl * e[0];
            g = sinl * e[1];
            e[1] = cosl * e[1];
            cr1 = cosr; sr1 = sinr; cl1 = cosl; sl1 = sinl;
            slartg_(f, g, cosr, sinr, r);
            e[0] = r;
            f = cosr * d[1] + sinr * e[1];
            e[1] = cosr * e[1] - sinr * d[1];
            g = sinr * d[2];
            d[2] = cosr * d[2];
            slartg_(f, g, cosl, sinl, r);
            d[1] = r;
            f = cosl * e[1] + sinl * d[2];
            d[2] = cosl * d[2] - sinl * e[1];
            cr2 = cosr; sr2 = sinr; cl2 = cosl; sl2 = sinl;
            e[1] = f;
            rot_rows<0, 1>(VT, cr1, sr1); rot_rows<1, 2>(VT, cr2, sr2);
            rot_cols<0, 1>(U, cl1, sl1);  rot_cols<1, 2>(U, cl2, sl2);
            if (fabsf(e[1]) <= thresh) e[1] = 0.0f;
        }
    }
    // ---- final 2x2 on rows 0..1 (reached after M:3->2 deflation) ----
    if (tail22 && !aborted) {
        if (fabsf(e[0]) <= thresh) {
            e[0] = 0.0f;
        } else {
            float sigmn, sigmx, sinr, cosr, sinl, cosl;
            slasv2_(d[0], e[0], d[1], sigmn, sigmx, sinr, cosr, sinl, cosl);
            d[0] = sigmx; d[1] = sigmn; e[0] = 0.0f;
            rot_rows<0, 1>(VT, cosr, sinr); rot_cols<0, 1>(U, cosl, sinl);
        }
    }
    // ---- un-mirror: U_out = VTarr^T, VT_out = Uarr^T, d unchanged ----
    if (mir) {
        float Un[3][3], Vn[3][3];
        #pragma unroll
        for (int i = 0; i < 3; ++i)
            #pragma unroll
            for (int j = 0; j < 3; ++j) { Un[i][j] = VT[j][i]; Vn[i][j] = U[j][i]; }
        #pragma unroll
        for (int i = 0; i < 3; ++i)
            #pragma unroll
            for (int j = 0; j < 3; ++j) { U[i][j] = Un[i][j]; VT[i][j] = Vn[i][j]; }
    }
    // ---- make singular values positive (flip VT rows only) ----
    #pragma unroll
    for (int i = 0; i < 3; ++i) {
        if (d[i] < 0.0f) {
            d[i] = -d[i];
            VT[i][0] = -VT[i][0]; VT[i][1] = -VT[i][1]; VT[i][2] = -VT[i][2];
        }
    }
    // ---- sort decreasing (LAPACK selection with <= tie-to-last) ----
    {
        int isub = 1; float smin = d[0];
        if (d[1] <= smin) { isub = 2; smin = d[1]; }
        if (d[2] <= smin) { isub = 3; smin = d[2]; }
        if (isub != 3) {
            if (isub == 1) { d[0] = d[2]; d[2] = smin; swap_rows<0, 2>(VT); swap_cols<0, 2>(U); }
            else           { d[1] = d[2]; d[2] = smin; swap_rows<1, 2>(VT); swap_cols<1, 2>(U); }
        }
    }
    {
        int isub = 1; float smin = d[0];
        if (d[1] <= smin) { isub = 2; smin = d[1]; }
        if (isub != 2) { d[0] = d[1]; d[1] = smin; swap_rows<0, 1>(VT); swap_cols<0, 1>(U); }
    }
}

// ===== SVD (SGEBD2 + SBDSQR) + ARAP energy from T, Srr, See =================
__device__ float svd_energy(const float T[3][3], float Srr, float See) {
    float A[3][3];
    #pragma unroll
    for (int i = 0; i < 3; ++i) { A[i][0] = T[i][0]; A[i][1] = T[i][1]; A[i][2] = T[i][2]; }

    float d[3], e[2];
    float tq0, v1, v2;
    float tp0, u2;
    float tq1, v22;
    {   // left reflector, column 0
        float a00 = A[0][0], a10 = A[1][0], a20 = A[2][0];
        float xn = fsqrt_(a10 * a10 + a20 * a20);
        if (xn == 0.0f) { tq0 = 0.0f; v1 = 0.0f; v2 = 0.0f; d[0] = a00; }
        else {
            float beta = -copysignf(fsqrt_(a00 * a00 + xn * xn), a00);
            tq0 = fdiv_(beta - a00, beta);
            float inv = fdiv_(1.0f, a00 - beta);
            v1 = a10 * inv; v2 = a20 * inv;
            d[0] = beta;
        }
        #pragma unroll
        for (int j = 1; j < 3; ++j) {
            float w = A[0][j] + v1 * A[1][j] + v2 * A[2][j];
            w *= tq0;
            A[0][j] -= w; A[1][j] -= w * v1; A[2][j] -= w * v2;
        }
    }
    {   // right reflector, row 0 cols 1..2
        float a01 = A[0][1], a02 = A[0][2];
        float xn = fabsf(a02);
        if (xn == 0.0f) { tp0 = 0.0f; u2 = 0.0f; e[0] = a01; }
        else {
            float beta = -copysignf(fsqrt_(a01 * a01 + a02 * a02), a01);
            tp0 = fdiv_(beta - a01, beta);
            u2 = fdiv_(a02, a01 - beta);
            e[0] = beta;
        }
        #pragma unroll
        for (int i = 1; i < 3; ++i) {
            float w = A[i][1] + u2 * A[i][2];
            w *= tp0;
            A[i][1] -= w; A[i][2] -= w * u2;
        }
    }
    {   // left reflector, column 1 rows 1..2
        float a11 = A[1][1], a21 = A[2][1];
        float xn = fabsf(a21);
        if (xn == 0.0f) { tq1 = 0.0f; v22 = 0.0f; d[1] = a11; }
        else {
            float beta = -copysignf(fsqrt_(a11 * a11 + a21 * a21), a11);
            tq1 = fdiv_(beta - a11, beta);
            v22 = fdiv_(a21, a11 - beta);
            d[1] = beta;
        }
        float w = A[1][2] + v22 * A[2][2];
        w *= tq1;
        A[1][2] -= w; A[2][2] -= w * v22;
        e[1] = A[1][2];
        d[2] = A[2][2];
    }

    float U[3][3], VT[3][3];
    {
        float h11 = 1.0f - tq1;
        float h12 = -tq1 * v22;
        float h22 = 1.0f - tq1 * v22 * v22;
        float w0 = 1.0f;
        float w1 = v1 * h11 + v2 * h12;
        float w2 = v1 * h12 + v2 * h22;
        U[0][0] = 1.0f - tq0 * w0;  U[0][1] = -tq0 * w1;           U[0][2] = -tq0 * w2;
        U[1][0] = -tq0 * v1 * w0;   U[1][1] = h11 - tq0 * v1 * w1; U[1][2] = h12 - tq0 * v1 * w2;
        U[2][0] = -tq0 * v2 * w0;   U[2][1] = h12 - tq0 * v2 * w1; U[2][2] = h22 - tq0 * v2 * w2;
        VT[0][0] = 1.0f; VT[0][1] = 0.0f;               VT[0][2] = 0.0f;
        VT[1][0] = 0.0f; VT[1][1] = 1.0f - tp0;         VT[1][2] = -tp0 * u2;
        VT[2][0] = 0.0f; VT[2][1] = -tp0 * u2;          VT[2][2] = 1.0f - tp0 * u2 * u2;
    }

    bdsqr3(d, e, U, VT);

    float detU = U[0][0] * (U[1][1] * U[2][2] - U[1][2] * U[2][1])
               - U[0][1] * (U[1][0] * U[2][2] - U[1][2] * U[2][0])
               + U[0][2] * (U[1][0] * U[2][1] - U[1][1] * U[2][0]);
    float detV = VT[0][0] * (VT[1][1] * VT[2][2] - VT[1][2] * VT[2][1])
               - VT[0][1] * (VT[1][0] * VT[2][2] - VT[1][2] * VT[2][0])
               + VT[0][2] * (VT[1][0] * VT[2][1] - VT[1][1] * VT[2][0]);
    float det = detU * detV;

    float cross = 0.0f;
    #pragma unroll
    for (int k = 0; k < 3; ++k) {
        float w0 = VT[k][0], w1 = VT[k][1], w2 = det * VT[k][2];
        #pragma unroll
        for (int i = 0; i < 3; ++i) {
            float Rik = U[i][0] * w0 + U[i][1] * w1 + U[i][2] * w2;
            cross += T[i][k] * Rik;
        }
    }
    return Srr + See - 2.0f * cross;
}

// ===== Phase B: gather + covariance, 8 lanes/vertex, 4 L2-resident slices ===
// Streaming inputs (nbrs/wgts) and output (Tout) use NON-TEMPORAL access so
// they don't evict the L2-resident table slice mid-pass.
__global__ __launch_bounds__(TPB, 4) void gather_kernel(
    const float4* __restrict__ P,
    const int*    __restrict__ nbrs, const float* __restrict__ wgts,
    float4* __restrict__ Tout)   // 3 float4 per vertex: T[9], Srr, See, pad
{
    const int t = blockIdx.x * TPB + threadIdx.x;
    const int v = t >> 3;
    const int p = t & 7;
    if (v >= NV) return;

    float4 a0 = P[(size_t)v * 2];
    float2 b0 = ((const float2*)P)[(size_t)v * 4 + 2];
    const float vx = a0.x, vy = a0.y, vz = a0.z;
    const float dx = a0.w, dy = b0.x, dz = b0.y;

    intx4   n0 = __builtin_nontemporal_load(((const intx4*)  (nbrs + (size_t)v * KN)) + p);
    floatx4 q0 = __builtin_nontemporal_load(((const floatx4*)(wgts + (size_t)v * KN)) + p);
    const int   ids[4] = { n0.x, n0.y, n0.z, n0.w };
    const float wss[4] = { q0.x, q0.y, q0.z, q0.w };

    float T00 = 0, T01 = 0, T02 = 0, T10 = 0, T11 = 0, T12 = 0, T20 = 0, T21 = 0, T22 = 0;
    float Srr = 0, See = 0;

    #pragma unroll
    for (int sl = 0; sl < NSLICE; ++sl) {
        const int lo = sl * SLICEW;
        const int hi = lo + SLICEW;
        #pragma unroll
        for (int k = 0; k < 4; ++k) {
            int nb = ids[k];
            if (nb >= lo && nb < hi) {
                float w  = wss[k];
                float4 a = P[(size_t)nb * 2];
                float2 b = ((const float2*)P)[(size_t)nb * 4 + 2];
                float e0 = a.x - vx, e1 = a.y - vy, e2 = a.z - vz;
                float r0 = a.w - dx, r1 = b.x - dy, r2 = b.y - dz;
                float we0 = w * e0, we1 = w * e1, we2 = w * e2;
                T00 += r0 * we0; T01 += r0 * we1; T02 += r0 * we2;
                T10 += r1 * we0; T11 += r1 * we1; T12 += r1 * we2;
                T20 += r2 * we0; T21 += r2 * we1; T22 += r2 * we2;
                Srr += w * (r0 * r0 + r1 * r1 + r2 * r2);
                See += we0 * e0 + we1 * e1 + we2 * e2;
            }
        }
    }

    #define RED8(x) x += __shfl_xor(x, 1); x += __shfl_xor(x, 2); x += __shfl_xor(x, 4);
    RED8(T00) RED8(T01) RED8(T02) RED8(T10) RED8(T11) RED8(T12)
    RED8(T20) RED8(T21) RED8(T22) RED8(Srr) RED8(See)
    #undef RED8

    floatx4* outv = (floatx4*)Tout;
    if (p == 0) { floatx4 o = { T00, T01, T02, T10 }; __builtin_nontemporal_store(o, outv + (size_t)v * 3 + 0); }
    if (p == 1) { floatx4 o = { T11, T12, T20, T21 }; __builtin_nontemporal_store(o, outv + (size_t)v * 3 + 1); }
    if (p == 2) { floatx4 o = { T22, Srr, See, 0.0f }; __builtin_nontemporal_store(o, outv + (size_t)v * 3 + 2); }
}

// ===== Phase C: SVD + energy, 1 thread per vertex ===========================
__global__ __launch_bounds__(TPB) void svd_kernel(
    const float4* __restrict__ Tin, float* __restrict__ out)
{
    __shared__ float s_red[TPB / 64];
    const int tid = threadIdx.x;
    const int n   = blockIdx.x * TPB + tid;
    float E = 0.0f;
    if (n < NV) {
        float4 q0 = Tin[(size_t)n * 3 + 0];
        float4 q1 = Tin[(size_t)n * 3 + 1];
        float4 q2 = Tin[(size_t)n * 3 + 2];
        float T[3][3] = {{q0.x, q0.y, q0.z}, {q0.w, q1.x, q1.y}, {q1.z, q1.w, q2.x}};
        E = svd_energy(T, q2.y, q2.z);
    }
    #pragma unroll
    for (int off = 32; off > 0; off >>= 1) E += __shfl_down(E, off);
    if ((tid & 63) == 0) s_red[tid >> 6] = E;
    __syncthreads();
    if (tid == 0) {
        float t = 0.0f;
        #pragma unroll
        for (int i = 0; i < TPB / 64; ++i) t += s_red[i];
        atomicAdd(out, t * (1.0f / (float)NV));
    }
}

// ===== fused fallback (used only if ws too small) ===========================
template<bool PACKED>
__global__ __launch_bounds__(TPB) void arap_fused(
    const float*  __restrict__ Vr, const float* __restrict__ Vdr,
    const float4* __restrict__ P,
    const int*    __restrict__ nbrs, const float* __restrict__ wgts,
    float* __restrict__ out)
{
    __shared__ float s_red[TPB / 64];
    const int tid = threadIdx.x;
    const int n   = blockIdx.x * TPB + tid;
    float E = 0.0f;
    if (n < NV) {
        float vx, vy, vz, dx, dy, dz;
        if (PACKED) {
            float4 a0 = P[(size_t)n * 2];
            float2 b0 = ((const float2*)P)[(size_t)n * 4 + 2];
            vx = a0.x; vy = a0.y; vz = a0.z; dx = a0.w; dy = b0.x; dz = b0.y;
        } else {
            vx = Vr [3 * n]; vy = Vr [3 * n + 1]; vz = Vr [3 * n + 2];
            dx = Vdr[3 * n]; dy = Vdr[3 * n + 1]; dz = Vdr[3 * n + 2];
        }
        float T[3][3] = {{0, 0, 0}, {0, 0, 0}, {0, 0, 0}};
        float Srr = 0.0f, See = 0.0f;
        for (int k = 0; k < KN; ++k) {
            int   nb = nbrs[(size_t)n * KN + k];
            float w  = wgts[(size_t)n * KN + k];
            float e0, e1, e2, r0, r1, r2;
            if (PACKED) {
                float4 a = P[(size_t)nb * 2];
                float2 b = ((const float2*)P)[(size_t)nb * 4 + 2];
                e0 = a.x - vx; e1 = a.y - vy; e2 = a.z - vz;
                r0 = a.w - dx; r1 = b.x - dy; r2 = b.y - dz;
            } else {
                e0 = Vr [3 * nb] - vx; e1 = Vr [3 * nb + 1] - vy; e2 = Vr [3 * nb + 2] - vz;
                r0 = Vdr[3 * nb] - dx; r1 = Vdr[3 * nb + 1] - dy; r2 = Vdr[3 * nb + 2] - dz;
            }
            float we0 = w * e0, we1 = w * e1, we2 = w * e2;
            T[0][0] += r0 * we0; T[0][1] += r0 * we1; T[0][2] += r0 * we2;
            T[1][0] += r1 * we0; T[1][1] += r1 * we1; T[1][2] += r1 * we2;
            T[2][0] += r2 * we0; T[2][1] += r2 * we1; T[2][2] += r2 * we2;
            Srr += w * (r0 * r0 + r1 * r1 + r2 * r2);
            See += we0 * e0 + we1 * e1 + we2 * e2;
        }
        E = svd_energy(T, Srr, See);
    }
    #pragma unroll
    for (int off = 32; off > 0; off >>= 1) E += __shfl_down(E, off);
    if ((tid & 63) == 0) s_red[tid >> 6] = E;
    __syncthreads();
    if (tid == 0) {
        float t = 0.0f;
        #pragma unroll
        for (int i = 0; i < TPB / 64; ++i) t += s_red[i];
        atomicAdd(out, t * (1.0f / (float)NV));
    }
}

extern "C" void kernel_launch(void* const* d_in, const int* in_sizes, int n_in,
                              void* d_out, int out_size, void* d_ws, size_t ws_size,
                              hipStream_t stream) {
    (void)in_sizes; (void)n_in; (void)out_size;
    const float* V  = (const float*)d_in[0];
    const float* Vd = (const float*)d_in[1];
    const int*   nb = (const int*)  d_in[2];
    const float* wg = (const float*)d_in[3];
    float* out = (float*)d_out;

    hipMemsetAsync(out, 0, sizeof(float), stream);

    const size_t tab_bytes  = (size_t)NV * 32;   // 6.4 MB packed table
    const size_t tmat_bytes = (size_t)NV * 48;   // 9.6 MB T-matrix buffer
    const int pblk = (NV * 3 + 255) / 256;

    if (ws_size >= tab_bytes + tmat_bytes) {
        float*  wsf  = (float*)d_ws;
        float4* tout = (float4*)((char*)d_ws + tab_bytes);
        pack_kernel<<<pblk, 256, 0, stream>>>(V, Vd, wsf);
        const int gblk = (NV * 8 + TPB - 1) / TPB;
        gather_kernel<<<gblk, TPB, 0, stream>>>((const float4*)wsf, nb, wg, tout);
        const int sblk = (NV + TPB - 1) / TPB;
        svd_kernel<<<sblk, TPB, 0, stream>>>((const float4*)tout, out);
    } else if (ws_size >= tab_bytes) {
        float* wsf = (float*)d_ws;
        pack_kernel<<<pblk, 256, 0, stream>>>(V, Vd, wsf);
        const int nblk = (NV + TPB - 1) / TPB;
        arap_fused<true><<<nblk, TPB, 0, stream>>>(nullptr, nullptr,
            (const float4*)wsf, nb, wg, out);
    } else {
        const int nblk = (NV + TPB - 1) / TPB;
        arap_fused<false><<<nblk, TPB, 0, stream>>>(V, Vd, nullptr, nb, wg, out);
    }
}

// Round 18
// 95.406 us; speedup vs baseline: 1.0991x; 1.0991x over previous
//
#include <hip/hip_runtime.h>
#include <hip/hip_bf16.h>

#define NV   200000
#define KN   32
#define TPB  256
#define NSLICE 4
#define SLICEW 50000   // NV / NSLICE; 50000*32B = 1.6 MB slice, L2-resident per XCD

// ===== LAPACK float32 machine constants =====
#define F_EPS  5.9604645e-8f    /* slamch('E') = 2^-24 */
#define F_UNFL 1.1754944e-38f   /* slamch('S') */
#define F_TOL  (10.0f * F_EPS)  /* tolmul = 10 */

// ===== fast math: conventions (signs/branches) follow LAPACK; 1-2 ulp
// rounding differences only flip decisions on measure-zero boundary sets.
__device__ __forceinline__ float fdiv_(float a, float b) { return __fdividef(a, b); }
__device__ __forceinline__ float fsqrt_(float x) { return __builtin_amdgcn_sqrtf(x); }

// ---- pack V / V_def into interleaved 32B records in workspace ---------------
// P[n] = { vx, vy, vz, dx, dy, dz, 0, 0 }
__global__ __launch_bounds__(256) void pack_kernel(const float* __restrict__ V,
                                                   const float* __restrict__ Vd,
                                                   float* __restrict__ wsf) {
    int i = blockIdx.x * 256 + threadIdx.x;
    if (i < NV * 3) {
        int n = i / 3;
        int c = i - n * 3;
        wsf[(size_t)n * 8 + c]     = V[i];
        wsf[(size_t)n * 8 + 3 + c] = Vd[i];
    }
}

// ===== LAPACK >=3.10 slartg (f32) ===========================================
__device__ __forceinline__ void slartg_(float f, float g, float& c, float& s, float& r) {
    if (g == 0.0f)      { c = 1.0f; s = 0.0f; r = f; }
    else if (f == 0.0f) { c = 0.0f; s = copysignf(1.0f, g); r = fabsf(g); }
    else {
        float d = fsqrt_(f * f + g * g);
        c = fdiv_(fabsf(f), d);
        r = copysignf(d, f);
        s = fdiv_(g, r);
    }
}

// ===== LAPACK slas2 (exactly symmetric under f<->h) =========================
__device__ __forceinline__ void slas2_(float f, float g, float h, float& ssmin, float& ssmax) {
    float fa = fabsf(f), ga = fabsf(g), ha = fabsf(h);
    float fhmn = fminf(fa, ha), fhmx = fmaxf(fa, ha);
    if (fhmn == 0.0f) {
        ssmin = 0.0f;
        if (fhmx == 0.0f) ssmax = ga;
        else {
            float mx = fmaxf(fhmx, ga), mn = fminf(fhmx, ga);
            float q = fdiv_(mn, mx);
            ssmax = mx * fsqrt_(1.0f + q * q);
        }
    } else {
        if (ga < fhmx) {
            float as_ = 1.0f + fdiv_(fhmn, fhmx);
            float at  = fdiv_(fhmx - fhmn, fhmx);
            float au  = fdiv_(ga, fhmx); au = au * au;
            float c   = fdiv_(2.0f, fsqrt_(as_ * as_ + au) + fsqrt_(at * at + au));
            ssmin = fhmn * c;
            ssmax = fdiv_(fhmx, c);
        } else {
            float au = fdiv_(fhmx, ga);
            if (au == 0.0f) { ssmin = fdiv_(fhmn * fhmx, ga); ssmax = ga; }
            else {
                float as_ = 1.0f + fdiv_(fhmn, fhmx);
                float at  = fdiv_(fhmx - fhmn, fhmx);
                float t1 = as_ * au, t2 = at * au;
                float c = fdiv_(1.0f, fsqrt_(1.0f + t1 * t1) + fsqrt_(1.0f + t2 * t2));
                ssmin = (fhmn * c) * au;
                ssmin = ssmin + ssmin;
                ssmax = fdiv_(ga, c + c);
            }
        }
    }
}

// ===== LAPACK slasv2 ========================================================
__device__ void slasv2_(float f, float g, float h,
                        float& ssmin, float& ssmax,
                        float& snr, float& csr, float& snl, float& csl) {
    float ft = f, fa = fabsf(f), ht = h, ha = fabsf(h);
    int pmax = 1;
    bool swp = (ha > fa);
    if (swp) {
        pmax = 3;
        float t = ft; ft = ht; ht = t;
        t = fa; fa = ha; ha = t;
    }
    float gt = g, ga = fabsf(g);
    float clt = 0.f, crt = 0.f, slt = 0.f, srt = 0.f;
    if (ga == 0.0f) {
        ssmin = ha; ssmax = fa;
        clt = 1.0f; crt = 1.0f; slt = 0.0f; srt = 0.0f;
    } else {
        bool gasmal = true;
        if (ga > fa) {
            pmax = 2;
            if (fdiv_(fa, ga) < F_EPS) {
                gasmal = false;
                ssmax = ga;
                ssmin = (ha > 1.0f) ? fdiv_(fa, fdiv_(ga, ha)) : (fdiv_(fa, ga) * ha);
                clt = 1.0f; slt = fdiv_(ht, gt); srt = 1.0f; crt = fdiv_(ft, gt);
            }
        }
        if (gasmal) {
            float dd = fa - ha;
            float l_ = (dd == fa) ? 1.0f : fdiv_(dd, fa);
            float m_ = fdiv_(gt, ft);
            float t_ = 2.0f - l_;
            float mm = m_ * m_, tt = t_ * t_;
            float s_ = fsqrt_(tt + mm);
            float r_ = (l_ == 0.0f) ? fabsf(m_) : fsqrt_(l_ * l_ + mm);
            float a_ = 0.5f * (s_ + r_);
            ssmin = fdiv_(ha, a_);
            ssmax = fa * a_;
            float tv;
            if (mm == 0.0f) {
                if (l_ == 0.0f) tv = copysignf(2.0f, ft) * copysignf(1.0f, gt);
                else            tv = fdiv_(gt, copysignf(dd, ft)) + fdiv_(m_, t_);
            } else {
                tv = (fdiv_(m_, s_ + t_) + fdiv_(m_, r_ + l_)) * (1.0f + a_);
            }
            float l2 = fsqrt_(tv * tv + 4.0f);
            crt = fdiv_(2.0f, l2);
            srt = fdiv_(tv, l2);
            clt = fdiv_(crt + srt * m_, a_);
            slt = fdiv_(ht, ft) * fdiv_(srt, a_);
        }
    }
    if (swp) { csl = srt; snl = crt; csr = slt; snr = clt; }
    else     { csl = clt; snl = slt; csr = crt; snr = srt; }
    float tsign = 1.0f;
    if (pmax == 1) tsign = copysignf(1.0f, csr) * copysignf(1.0f, csl) * copysignf(1.0f, f);
    if (pmax == 2) tsign = copysignf(1.0f, snr) * copysignf(1.0f, csl) * copysignf(1.0f, g);
    if (pmax == 3) tsign = copysignf(1.0f, snr) * copysignf(1.0f, snl) * copysignf(1.0f, h);
    ssmax = copysignf(ssmax, tsign);
    ssmin = copysignf(ssmin, tsign * copysignf(1.0f, f) * copysignf(1.0f, h));
}

// ===== static-index helpers =================================================
template<int RA, int RB>
__device__ __forceinline__ void rot_rows(float A[3][3], float c, float s) {
    #pragma unroll
    for (int j = 0; j < 3; ++j) {
        float x = A[RA][j], y = A[RB][j];
        A[RA][j] = c * x + s * y;
        A[RB][j] = c * y - s * x;
    }
}
template<int CA, int CB>
__device__ __forceinline__ void rot_cols(float A[3][3], float c, float s) {
    #pragma unroll
    for (int i = 0; i < 3; ++i) {
        float x = A[i][CA], y = A[i][CB];
        A[i][CA] = c * x + s * y;
        A[i][CB] = c * y - s * x;
    }
}
template<int RA, int RB>
__device__ __forceinline__ void swap_rows(float A[3][3]) {
    #pragma unroll
    for (int j = 0; j < 3; ++j) { float t = A[RA][j]; A[RA][j] = A[RB][j]; A[RB][j] = t; }
}
template<int CA, int CB>
__device__ __forceinline__ void swap_cols(float A[3][3]) {
    #pragma unroll
    for (int i = 0; i < 3; ++i) { float t = A[i][CA]; A[i][CA] = A[i][CB]; A[i][CB] = t; }
}

// ===== SBDSQR for n=3: single-direction via exact mirror ====================
// (idir==2 == J-conjugate of idir==1; mirror up front, run idir=1 loop only,
// un-mirror before the common epilogue. See round-13 derivation.)
__device__ void bdsqr3(float d[3], float e[2], float U[3][3], float VT[3][3]) {
    float thresh;
    {   // thresh on ORIGINAL orientation (LAPACK computes it before idir)
        float sminoa = fabsf(d[0]);
        if (sminoa != 0.0f) {
            float mu = sminoa;
            mu = fabsf(d[1]) * fdiv_(mu, mu + fabsf(e[0]));
            sminoa = fminf(sminoa, mu);
            if (sminoa != 0.0f) {
                mu = fabsf(d[2]) * fdiv_(mu, mu + fabsf(e[1]));
                sminoa = fminf(sminoa, mu);
            }
        }
        sminoa = sminoa * 0.57735026919f;   // /sqrt(3)
        thresh = fmaxf(F_TOL * sminoa, 54.0f * F_UNFL);
    }

    const bool mir = fabsf(d[0]) < fabsf(d[2]);
    if (mir) {
        float t = d[0]; d[0] = d[2]; d[2] = t;
        t = e[0]; e[0] = e[1]; e[1] = t;
        float Un[3][3], Vn[3][3];
        #pragma unroll
        for (int i = 0; i < 3; ++i)
            #pragma unroll
            for (int j = 0; j < 3; ++j) { Un[i][j] = VT[2 - j][i]; Vn[i][j] = U[j][2 - i]; }
        #pragma unroll
        for (int i = 0; i < 3; ++i)
            #pragma unroll
            for (int j = 0; j < 3; ++j) { U[i][j] = Un[i][j]; VT[i][j] = Vn[i][j]; }
    }

    int iter = 0;
    bool tail22 = false;   // deflated to leading 2x2 (rows 0..1)
    bool aborted = false;

    for (;;) {
        if (iter > 54) { aborted = true; break; }
        // ---- bottom-up negligibility scan (static) ----
        if (fabsf(e[1]) <= thresh) { e[1] = 0.0f; tail22 = true; break; }   // M: 3->2
        float smax = fmaxf(fabsf(d[2]), fmaxf(fabsf(e[1]), fabsf(d[1])));
        if (fabsf(e[0]) <= thresh) {
            // block = rows 1..2: 2x2 slasv2, then M=1 -> done
            e[0] = 0.0f;
            float sigmn, sigmx, sinr, cosr, sinl, cosl;
            slasv2_(d[1], e[1], d[2], sigmn, sigmx, sinr, cosr, sinl, cosl);
            d[1] = sigmx; d[2] = sigmn; e[1] = 0.0f;
            rot_rows<1, 2>(VT, cosr, sinr); rot_cols<1, 2>(U, cosl, sinl);
            break;
        }
        smax = fmaxf(smax, fmaxf(fabsf(e[0]), fabsf(d[0])));
        // ---- full 3x3 block, idir==1 semantics only (mirror guarantees) ----
        float sminl = 0.0f;
        bool conv = false;
        {
            if (fabsf(e[1]) <= F_TOL * fabsf(d[2])) { e[1] = 0.0f; continue; }
            float mu = fabsf(d[0]); sminl = mu;
            if (fabsf(e[0]) <= F_TOL * mu) { e[0] = 0.0f; conv = true; }
            else {
                mu = fabsf(d[1]) * fdiv_(mu, mu + fabsf(e[0]));
                sminl = fminf(sminl, mu);
                if (fabsf(e[1]) <= F_TOL * mu) { e[1] = 0.0f; conv = true; }
                else {
                    mu = fabsf(d[2]) * fdiv_(mu, mu + fabsf(e[1]));
                    sminl = fminf(sminl, mu);
                }
            }
        }
        if (conv) continue;
        // ---- shift ----
        float shift = 0.0f, rdum;
        if (3.0f * F_TOL * fdiv_(sminl, smax) <= fmaxf(F_EPS, 0.01f * F_TOL)) {
            shift = 0.0f;
        } else {
            float sll = fabsf(d[0]);
            slas2_(d[1], e[1], d[2], shift, rdum);
            if (sll > 0.0f) { float q = fdiv_(shift, sll); if (q * q < F_EPS) shift = 0.0f; }
        }
        iter += 2;
        // ---- one QR sweep, idir==1 bodies only ----
        if (shift == 0.0f) {
            float cs = 1.0f, oldcs = 1.0f, sn, oldsn, r;
            float c1, s1, oc1, os1, c2, s2, oc2, os2;
            slartg_(d[0] * cs, e[0], cs, sn, r);
            slartg_(oldcs * r, d[1] * sn, oldcs, oldsn, d[0]);
            c1 = cs; s1 = sn; oc1 = oldcs; os1 = oldsn;
            slartg_(d[1] * cs, e[1], cs, sn, r);
            e[0] = oldsn * r;
            slartg_(oldcs * r, d[2] * sn, oldcs, oldsn, d[1]);
            c2 = cs; s2 = sn; oc2 = oldcs; os2 = oldsn;
            float h = d[2] * cs; d[2] = h * oldcs; e[1] = h * oldsn;
            rot_rows<0, 1>(VT, c1, s1);  rot_rows<1, 2>(VT, c2, s2);
            rot_cols<0, 1>(U, oc1, os1); rot_cols<1, 2>(U, oc2, os2);
            if (fabsf(e[1]) <= thresh) e[1] = 0.0f;
        } else {
            float f = (fabsf(d[0]) - shift) * (copysignf(1.0f, d[0]) + fdiv_(shift, d[0]));
            float g = e[0], cosr, sinr, cosl, sinl, r;
            float cr1, sr1, cl1, sl1, cr2, sr2, cl2, sl2;
            slartg_(f, g, cosr, sinr, r);
            f = cosr * d[0] + sinr * e[0];
            e[0] = cosr * e[0] - sinr * d[0];
            g = sinr * d[1];
            d[1] = cosr * d[1];
            slartg_(f, g, cosl, sinl, r);
            d[0] = r;
            f = cosl * e[0] + sinl * d[1];
            d[1] = cosl * d[1] - sinl * e[0];
            g = sinl * e[1];
            e[1] = cosl * e[1];
            cr1 = cosr; sr1 = sinr; cl1 = cosl; sl1 = sinl;
            slartg_(f, g, cosr, sinr, r);
            e[0] = r;
            f = cosr * d[1] + sinr * e[1];
            e[1] = cosr * e[1] - sinr * d[1];
            g = sinr * d[2];
            d[2] = cosr * d[2];
            slartg_(f, g, cosl, sinl, r);
            d[1] = r;
            f = cosl * e[1] + sinl * d[2];
            d[2] = cosl * d[2] - sinl * e[1];
            cr2 = cosr; sr2 = sinr; cl2 = cosl; sl2 = sinl;
            e[1] = f;
            rot_rows<0, 1>(VT, cr1, sr1); rot_rows<1, 2>(VT, cr2, sr2);
            rot_cols<0, 1>(U, cl1, sl1);  rot_cols<1, 2>(U, cl2, sl2);
            if (fabsf(e[1]) <= thresh) e[1] = 0.0f;
        }
    }
    // ---- final 2x2 on rows 0..1 (reached after M:3->2 deflation) ----
    if (tail22 && !aborted) {
        if (fabsf(e[0]) <= thresh) {
            e[0] = 0.0f;
        } else {
            float sigmn, sigmx, sinr, cosr, sinl, cosl;
            slasv2_(d[0], e[0], d[1], sigmn, sigmx, sinr, cosr, sinl, cosl);
            d[0] = sigmx; d[1] = sigmn; e[0] = 0.0f;
            rot_rows<0, 1>(VT, cosr, sinr); rot_cols<0, 1>(U, cosl, sinl);
        }
    }
    // ---- un-mirror: U_out = VTarr^T, VT_out = Uarr^T, d unchanged ----
    if (mir) {
        float Un[3][3], Vn[3][3];
        #pragma unroll
        for (int i = 0; i < 3; ++i)
            #pragma unroll
            for (int j = 0; j < 3; ++j) { Un[i][j] = VT[j][i]; Vn[i][j] = U[j][i]; }
        #pragma unroll
        for (int i = 0; i < 3; ++i)
            #pragma unroll
            for (int j = 0; j < 3; ++j) { U[i][j] = Un[i][j]; VT[i][j] = Vn[i][j]; }
    }
    // ---- make singular values positive (flip VT rows only) ----
    #pragma unroll
    for (int i = 0; i < 3; ++i) {
        if (d[i] < 0.0f) {
            d[i] = -d[i];
            VT[i][0] = -VT[i][0]; VT[i][1] = -VT[i][1]; VT[i][2] = -VT[i][2];
        }
    }
    // ---- sort decreasing (LAPACK selection with <= tie-to-last) ----
    {
        int isub = 1; float smin = d[0];
        if (d[1] <= smin) { isub = 2; smin = d[1]; }
        if (d[2] <= smin) { isub = 3; smin = d[2]; }
        if (isub != 3) {
            if (isub == 1) { d[0] = d[2]; d[2] = smin; swap_rows<0, 2>(VT); swap_cols<0, 2>(U); }
            else           { d[1] = d[2]; d[2] = smin; swap_rows<1, 2>(VT); swap_cols<1, 2>(U); }
        }
    }
    {
        int isub = 1; float smin = d[0];
        if (d[1] <= smin) { isub = 2; smin = d[1]; }
        if (isub != 2) { d[0] = d[1]; d[1] = smin; swap_rows<0, 1>(VT); swap_cols<0, 1>(U); }
    }
}

// ===== SVD (SGEBD2 + SBDSQR) + ARAP energy from T, Srr, See =================
__device__ float svd_energy(const float T[3][3], float Srr, float See) {
    float A[3][3];
    #pragma unroll
    for (int i = 0; i < 3; ++i) { A[i][0] = T[i][0]; A[i][1] = T[i][1]; A[i][2] = T[i][2]; }

    float d[3], e[2];
    float tq0, v1, v2;
    float tp0, u2;
    float tq1, v22;
    {   // left reflector, column 0
        float a00 = A[0][0], a10 = A[1][0], a20 = A[2][0];
        float xn = fsqrt_(a10 * a10 + a20 * a20);
        if (xn == 0.0f) { tq0 = 0.0f; v1 = 0.0f; v2 = 0.0f; d[0] = a00; }
        else {
            float beta = -copysignf(fsqrt_(a00 * a00 + xn * xn), a00);
            tq0 = fdiv_(beta - a00, beta);
            float inv = fdiv_(1.0f, a00 - beta);
            v1 = a10 * inv; v2 = a20 * inv;
            d[0] = beta;
        }
        #pragma unroll
        for (int j = 1; j < 3; ++j) {
            float w = A[0][j] + v1 * A[1][j] + v2 * A[2][j];
            w *= tq0;
            A[0][j] -= w; A[1][j] -= w * v1; A[2][j] -= w * v2;
        }
    }
    {   // right reflector, row 0 cols 1..2
        float a01 = A[0][1], a02 = A[0][2];
        float xn = fabsf(a02);
        if (xn == 0.0f) { tp0 = 0.0f; u2 = 0.0f; e[0] = a01; }
        else {
            float beta = -copysignf(fsqrt_(a01 * a01 + a02 * a02), a01);
            tp0 = fdiv_(beta - a01, beta);
            u2 = fdiv_(a02, a01 - beta);
            e[0] = beta;
        }
        #pragma unroll
        for (int i = 1; i < 3; ++i) {
            float w = A[i][1] + u2 * A[i][2];
            w *= tp0;
            A[i][1] -= w; A[i][2] -= w * u2;
        }
    }
    {   // left reflector, column 1 rows 1..2
        float a11 = A[1][1], a21 = A[2][1];
        float xn = fabsf(a21);
        if (xn == 0.0f) { tq1 = 0.0f; v22 = 0.0f; d[1] = a11; }
        else {
            float beta = -copysignf(fsqrt_(a11 * a11 + a21 * a21), a11);
            tq1 = fdiv_(beta - a11, beta);
            v22 = fdiv_(a21, a11 - beta);
            d[1] = beta;
        }
        float w = A[1][2] + v22 * A[2][2];
        w *= tq1;
        A[1][2] -= w; A[2][2] -= w * v22;
        e[1] = A[1][2];
        d[2] = A[2][2];
    }

    float U[3][3], VT[3][3];
    {
        float h11 = 1.0f - tq1;
        float h12 = -tq1 * v22;
        float h22 = 1.0f - tq1 * v22 * v22;
        float w0 = 1.0f;
        float w1 = v1 * h11 + v2 * h12;
        float w2 = v1 * h12 + v2 * h22;
        U[0][0] = 1.0f - tq0 * w0;  U[0][1] = -tq0 * w1;           U[0][2] = -tq0 * w2;
        U[1][0] = -tq0 * v1 * w0;   U[1][1] = h11 - tq0 * v1 * w1; U[1][2] = h12 - tq0 * v1 * w2;
        U[2][0] = -tq0 * v2 * w0;   U[2][1] = h12 - tq0 * v2 * w1; U[2][2] = h22 - tq0 * v2 * w2;
        VT[0][0] = 1.0f; VT[0][1] = 0.0f;               VT[0][2] = 0.0f;
        VT[1][0] = 0.0f; VT[1][1] = 1.0f - tp0;         VT[1][2] = -tp0 * u2;
        VT[2][0] = 0.0f; VT[2][1] = -tp0 * u2;          VT[2][2] = 1.0f - tp0 * u2 * u2;
    }

    bdsqr3(d, e, U, VT);

    float detU = U[0][0] * (U[1][1] * U[2][2] - U[1][2] * U[2][1])
               - U[0][1] * (U[1][0] * U[2][2] - U[1][2] * U[2][0])
               + U[0][2] * (U[1][0] * U[2][1] - U[1][1] * U[2][0]);
    float detV = VT[0][0] * (VT[1][1] * VT[2][2] - VT[1][2] * VT[2][1])
               - VT[0][1] * (VT[1][0] * VT[2][2] - VT[1][2] * VT[2][0])
               + VT[0][2] * (VT[1][0] * VT[2][1] - VT[1][1] * VT[2][0]);
    float det = detU * detV;

    float cross = 0.0f;
    #pragma unroll
    for (int k = 0; k < 3; ++k) {
        float w0 = VT[k][0], w1 = VT[k][1], w2 = det * VT[k][2];
        #pragma unroll
        for (int i = 0; i < 3; ++i) {
            float Rik = U[i][0] * w0 + U[i][1] * w1 + U[i][2] * w2;
            cross += T[i][k] * Rik;
        }
    }
    return Srr + See - 2.0f * cross;
}

// ===== Phase B: gather + covariance, 4 lanes/vertex, 4 L2-resident slices ===
// (round-5 proven config: ~51 us; 4 lanes x 8 nbrs halves redundant
// own-vertex loads vs the 8-lane split and doubles per-lane ILP)
__global__ __launch_bounds__(TPB, 4) void gather_kernel(
    const float4* __restrict__ P,
    const int*    __restrict__ nbrs, const float* __restrict__ wgts,
    float4* __restrict__ Tout)   // 3 float4 per vertex: T[9], Srr, See, pad
{
    const int t = blockIdx.x * TPB + threadIdx.x;
    const int v = t >> 2;
    const int p = t & 3;
    if (v >= NV) return;

    float4 a0 = P[(size_t)v * 2];
    float2 b0 = ((const float2*)P)[(size_t)v * 4 + 2];
    const float vx = a0.x, vy = a0.y, vz = a0.z;
    const float dx = a0.w, dy = b0.x, dz = b0.y;

    const int4*   nb4 = (const int4*)  (nbrs + (size_t)v * KN) + p * 2;
    const float4* w4  = (const float4*)(wgts + (size_t)v * KN) + p * 2;
    int4   n0 = nb4[0], n1 = nb4[1];
    float4 q0 = w4[0],  q1 = w4[1];
    const int   ids[8] = { n0.x, n0.y, n0.z, n0.w, n1.x, n1.y, n1.z, n1.w };
    const float wss[8] = { q0.x, q0.y, q0.z, q0.w, q1.x, q1.y, q1.z, q1.w };

    float T00 = 0, T01 = 0, T02 = 0, T10 = 0, T11 = 0, T12 = 0, T20 = 0, T21 = 0, T22 = 0;
    float Srr = 0, See = 0;

    // Pass over 4 contiguous table slices (1.6 MB each) so random gathers stay
    // L2-resident per XCD. Sum order changes vs k-order: ~ulp effect only.
    #pragma unroll
    for (int sl = 0; sl < NSLICE; ++sl) {
        const int lo = sl * SLICEW;
        const int hi = lo + SLICEW;
        #pragma unroll
        for (int k = 0; k < 8; ++k) {
            int nb = ids[k];
            if (nb >= lo && nb < hi) {
                float w  = wss[k];
                float4 a = P[(size_t)nb * 2];
                float2 b = ((const float2*)P)[(size_t)nb * 4 + 2];
                float e0 = a.x - vx, e1 = a.y - vy, e2 = a.z - vz;
                float r0 = a.w - dx, r1 = b.x - dy, r2 = b.y - dz;
                float we0 = w * e0, we1 = w * e1, we2 = w * e2;
                T00 += r0 * we0; T01 += r0 * we1; T02 += r0 * we2;
                T10 += r1 * we0; T11 += r1 * we1; T12 += r1 * we2;
                T20 += r2 * we0; T21 += r2 * we1; T22 += r2 * we2;
                Srr += w * (r0 * r0 + r1 * r1 + r2 * r2);
                See += we0 * e0 + we1 * e1 + we2 * e2;
            }
        }
    }

    // butterfly over the 4-lane group
    #define RED4(x) x += __shfl_xor(x, 1); x += __shfl_xor(x, 2);
    RED4(T00) RED4(T01) RED4(T02) RED4(T10) RED4(T11) RED4(T12)
    RED4(T20) RED4(T21) RED4(T22) RED4(Srr) RED4(See)
    #undef RED4

    if (p == 0) Tout[(size_t)v * 3 + 0] = make_float4(T00, T01, T02, T10);
    if (p == 1) Tout[(size_t)v * 3 + 1] = make_float4(T11, T12, T20, T21);
    if (p == 2) Tout[(size_t)v * 3 + 2] = make_float4(T22, Srr, See, 0.0f);
}

// ===== Phase C: SVD + energy, 1 thread per vertex ===========================
__global__ __launch_bounds__(TPB) void svd_kernel(
    const float4* __restrict__ Tin, float* __restrict__ out)
{
    __shared__ float s_red[TPB / 64];
    const int tid = threadIdx.x;
    const int n   = blockIdx.x * TPB + tid;
    float E = 0.0f;
    if (n < NV) {
        float4 q0 = Tin[(size_t)n * 3 + 0];
        float4 q1 = Tin[(size_t)n * 3 + 1];
        float4 q2 = Tin[(size_t)n * 3 + 2];
        float T[3][3] = {{q0.x, q0.y, q0.z}, {q0.w, q1.x, q1.y}, {q1.z, q1.w, q2.x}};
        E = svd_energy(T, q2.y, q2.z);
    }
    #pragma unroll
    for (int off = 32; off > 0; off >>= 1) E += __shfl_down(E, off);
    if ((tid & 63) == 0) s_red[tid >> 6] = E;
    __syncthreads();
    if (tid == 0) {
        float t = 0.0f;
        #pragma unroll
        for (int i = 0; i < TPB / 64; ++i) t += s_red[i];
        atomicAdd(out, t * (1.0f / (float)NV));
    }
}

// ===== fused fallback (used only if ws too small) ===========================
template<bool PACKED>
__global__ __launch_bounds__(TPB) void arap_fused(
    const float*  __restrict__ Vr, const float* __restrict__ Vdr,
    const float4* __restrict__ P,
    const int*    __restrict__ nbrs, const float* __restrict__ wgts,
    float* __restrict__ out)
{
    __shared__ float s_red[TPB / 64];
    const int tid = threadIdx.x;
    const int n   = blockIdx.x * TPB + tid;
    float E = 0.0f;
    if (n < NV) {
        float vx, vy, vz, dx, dy, dz;
        if (PACKED) {
            float4 a0 = P[(size_t)n * 2];
            float2 b0 = ((const float2*)P)[(size_t)n * 4 + 2];
            vx = a0.x; vy = a0.y; vz = a0.z; dx = a0.w; dy = b0.x; dz = b0.y;
        } else {
            vx = Vr [3 * n]; vy = Vr [3 * n + 1]; vz = Vr [3 * n + 2];
            dx = Vdr[3 * n]; dy = Vdr[3 * n + 1]; dz = Vdr[3 * n + 2];
        }
        float T[3][3] = {{0, 0, 0}, {0, 0, 0}, {0, 0, 0}};
        float Srr = 0.0f, See = 0.0f;
        for (int k = 0; k < KN; ++k) {
            int   nb = nbrs[(size_t)n * KN + k];
            float w  = wgts[(size_t)n * KN + k];
            float e0, e1, e2, r0, r1, r2;
            if (PACKED) {
                float4 a = P[(size_t)nb * 2];
                float2 b = ((const float2*)P)[(size_t)nb * 4 + 2];
                e0 = a.x - vx; e1 = a.y - vy; e2 = a.z - vz;
                r0 = a.w - dx; r1 = b.x - dy; r2 = b.y - dz;
            } else {
                e0 = Vr [3 * nb] - vx; e1 = Vr [3 * nb + 1] - vy; e2 = Vr [3 * nb + 2] - vz;
                r0 = Vdr[3 * nb] - dx; r1 = Vdr[3 * nb + 1] - dy; r2 = Vdr[3 * nb + 2] - dz;
            }
            float we0 = w * e0, we1 = w * e1, we2 = w * e2;
            T[0][0] += r0 * we0; T[0][1] += r0 * we1; T[0][2] += r0 * we2;
            T[1][0] += r1 * we0; T[1][1] += r1 * we1; T[1][2] += r1 * we2;
            T[2][0] += r2 * we0; T[2][1] += r2 * we1; T[2][2] += r2 * we2;
            Srr += w * (r0 * r0 + r1 * r1 + r2 * r2);
            See += we0 * e0 + we1 * e1 + we2 * e2;
        }
        E = svd_energy(T, Srr, See);
    }
    #pragma unroll
    for (int off = 32; off > 0; off >>= 1) E += __shfl_down(E, off);
    if ((tid & 63) == 0) s_red[tid >> 6] = E;
    __syncthreads();
    if (tid == 0) {
        float t = 0.0f;
        #pragma unroll
        for (int i = 0; i < TPB / 64; ++i) t += s_red[i];
        atomicAdd(out, t * (1.0f / (float)NV));
    }
}

extern "C" void kernel_launch(void* const* d_in, const int* in_sizes, int n_in,
                              void* d_out, int out_size, void* d_ws, size_t ws_size,
                              hipStream_t stream) {
    (void)in_sizes; (void)n_in; (void)out_size;
    const float* V  = (const float*)d_in[0];
    const float* Vd = (const float*)d_in[1];
    const int*   nb = (const int*)  d_in[2];
    const float* wg = (const float*)d_in[3];
    float* out = (float*)d_out;

    hipMemsetAsync(out, 0, sizeof(float), stream);

    const size_t tab_bytes  = (size_t)NV * 32;   // 6.4 MB packed table
    const size_t tmat_bytes = (size_t)NV * 48;   // 9.6 MB T-matrix buffer
    const int pblk = (NV * 3 + 255) / 256;

    if (ws_size >= tab_bytes + tmat_bytes) {
        float*  wsf  = (float*)d_ws;
        float4* tout = (float4*)((char*)d_ws + tab_bytes);
        pack_kernel<<<pblk, 256, 0, stream>>>(V, Vd, wsf);
        const int gblk = (NV * 4 + TPB - 1) / TPB;
        gather_kernel<<<gblk, TPB, 0, stream>>>((const float4*)wsf, nb, wg, tout);
        const int sblk = (NV + TPB - 1) / TPB;
        svd_kernel<<<sblk, TPB, 0, stream>>>((const float4*)tout, out);
    } else if (ws_size >= tab_bytes) {
        float* wsf = (float*)d_ws;
        pack_kernel<<<pblk, 256, 0, stream>>>(V, Vd, wsf);
        const int nblk = (NV + TPB - 1) / TPB;
        arap_fused<true><<<nblk, TPB, 0, stream>>>(nullptr, nullptr,
            (const float4*)wsf, nb, wg, out);
    } else {
        const int nblk = (NV + TPB - 1) / TPB;
        arap_fused<false><<<nblk, TPB, 0, stream>>>(V, Vd, nullptr, nb, wg, out);
    }
}